// Round 8
// baseline (90.549 us; speedup 1.0000x reference)
//
#include <hip/hip_runtime.h>

#define NBATCH 256
#define NCH 30
#define UF 4

__device__ __forceinline__ float fast_sqrt(float x) {
    float r;
    asm("v_sqrt_f32 %0, %1" : "=v"(r) : "v"(x));
    return r;
}

// Grid ≡ 0 (mod 15) -> 4*T ≡ 0 (mod 30): per-thread channel phase c0 and the
// LDS slot (cell0 - cb) are batch-invariant. Conf values come from the block's
// own loaded registers via one LDS exchange (no per-thread conf global loads:
// those cost a full VMEM issue slot each and were half our VMEM instructions).
// w(c, obj) = obj*A + B:  c<4 -> (5,0);  c==4 -> (0.5,0.5);  c>=5 -> (1,0).
__global__ __launch_bounds__(256, 4) void yolo_loss_kernel(
    const float* __restrict__ pred,
    const float* __restrict__ targ,
    float* __restrict__ out,
    int n4)
{
    const int T   = gridDim.x * blockDim.x;     // 5880*256 = 1,505,280
    const int tid = blockIdx.x * blockDim.x + threadIdx.x;

    const int e0    = tid * 4;
    const int c0    = e0 % NCH;                 // even; batch-invariant
    const int cell0 = e0 / NCH;

    // per-slot channel table (k -> channel c0+k mod 30)
    float A[4], B[4];
    bool  SQ[4];
    #pragma unroll
    for (int k = 0; k < 4; ++k) {
        int c = c0 + k; if (c >= NCH) c -= NCH;
        SQ[k] = (c == 2 || c == 3);
        if (c < 4)       { A[k] = 5.0f; B[k] = 0.0f; }
        else if (c == 4) { A[k] = 0.5f; B[k] = 0.5f; }
        else             { A[k] = 1.0f; B[k] = 0.0f; }
    }

    const float4* __restrict__ p4 = reinterpret_cast<const float4*>(pred);
    const float4* __restrict__ t4 = reinterpret_cast<const float4*>(targ);

    __shared__ float lconf[UF][40];   // per-batch confs for the block's cells
    float acc = 0.0f;

    if (n4 == UF * T) {
        // ---------- fast path (shipped shape) ----------
        const int K4T  = 4 * T;                 // element stride per batch
        const int B0   = blockIdx.x * 1024;     // block batch-0 element base
        const int cb   = B0 / NCH;              // block cell base (batch-inv slot origin)
        const int slot = cell0 - cb;            // 0..34

        float4 pv0 = p4[tid + 0*T], tv0 = t4[tid + 0*T];
        float4 pv1 = p4[tid + 1*T], tv1 = t4[tid + 1*T];
        float4 pv2 = p4[tid + 2*T], tv2 = t4[tid + 2*T];
        float4 pv3 = p4[tid + 3*T], tv3 = t4[tid + 3*T];

        // edge confs (first/last cell of the block span may fall outside it)
        if (threadIdx.x == 0) {
            const int cl = (B0 + 1023) / NCH;   // last covered cell
            #pragma unroll
            for (int u = 0; u < UF; ++u) {
                lconf[u][0]       = targ[NCH*cb + 4 + u*K4T];
                lconf[u][cl - cb] = targ[NCH*cl + 4 + u*K4T];
            }
        }
        // in-range confs straight from registers (c0==4 -> elem0, c0==2 -> elem2)
        if (c0 == 2 || c0 == 4) {
            lconf[0][slot] = (c0 == 4) ? tv0.x : tv0.z;
            lconf[1][slot] = (c0 == 4) ? tv1.x : tv1.z;
            lconf[2][slot] = (c0 == 4) ? tv2.x : tv2.z;
            lconf[3][slot] = (c0 == 4) ? tv3.x : tv3.z;
        }
        __syncthreads();

        #define CONSUME(U, PV, TV) {                                          \
            float clo = lconf[U][slot];                                       \
            float chr = lconf[U][slot + 1];         /* in-bounds: <=36<40 */  \
            float chi = (c0 == 28) ? chr : clo;     /* only phase 28 straddles */ \
            float obj01 = (clo == 1.0f) ? 1.0f : 0.0f;                        \
            float obj23 = (chi == 1.0f) ? 1.0f : 0.0f;                        \
            float pe[4] = {PV.x, PV.y, PV.z, PV.w};                           \
            float te[4] = {TV.x, TV.y, TV.z, TV.w};                           \
            _Pragma("unroll")                                                 \
            for (int k = 0; k < 4; ++k) {                                     \
                float p = pe[k], t = te[k];                                   \
                float dns = p - t;                                            \
                float vns = dns * dns;                                        \
                float vsq = (p + t) - 2.0f * fast_sqrt(p * t);                \
                float val = SQ[k] ? vsq : vns;                                \
                float ob  = (k < 2) ? obj01 : obj23;                          \
                float w   = fmaf(ob, A[k], B[k]);                             \
                acc = fmaf(w, val, acc);                                      \
            }                                                                 \
        }

        CONSUME(0, pv0, tv0)
        CONSUME(1, pv1, tv1)
        CONSUME(2, pv2, tv2)
        CONSUME(3, pv3, tv3)
        #undef CONSUME
    } else {
        // ---------- generic fallback (any n4) ----------
        for (int i = tid; i < n4; i += T) {
            float4 pv = p4[i];
            float4 tv = t4[i];
            int ee   = i * 4;
            int clLo = ee / NCH;
            int clHi = (ee + 3) / NCH;
            float clo = targ[clLo * NCH + 4];
            float chi = targ[clHi * NCH + 4];
            float obj01 = (clo == 1.0f) ? 1.0f : 0.0f;
            float obj23 = (chi == 1.0f) ? 1.0f : 0.0f;
            float pe[4] = {pv.x, pv.y, pv.z, pv.w};
            float te[4] = {tv.x, tv.y, tv.z, tv.w};
            #pragma unroll
            for (int k = 0; k < 4; ++k) {
                float p = pe[k], t = te[k];
                float dns = p - t;
                float vns = dns * dns;
                float vsq = (p + t) - 2.0f * fast_sqrt(p * t);
                float val = SQ[k] ? vsq : vns;
                float ob  = (k < 2) ? obj01 : obj23;
                float w   = fmaf(ob, A[k], B[k]);
                acc = fmaf(w, val, acc);
            }
        }
    }

    // wave64 shuffle reduction -> block LDS -> one atomic per block
    #pragma unroll
    for (int off = 32; off > 0; off >>= 1)
        acc += __shfl_down(acc, off, 64);

    __shared__ float lds[4];
    int lane = threadIdx.x & 63;
    int wid  = threadIdx.x >> 6;
    if (lane == 0) lds[wid] = acc;
    __syncthreads();
    if (threadIdx.x == 0) {
        float s = lds[0] + lds[1] + lds[2] + lds[3];
        atomicAdd(out, s * (1.0f / (float)NBATCH));
    }
}

extern "C" void kernel_launch(void* const* d_in, const int* in_sizes, int n_in,
                              void* d_out, int out_size, void* d_ws, size_t ws_size,
                              hipStream_t stream)
{
    const float* pred = (const float*)d_in[0];
    const float* targ = (const float*)d_in[1];
    float* out = (float*)d_out;

    hipMemsetAsync(out, 0, sizeof(float), stream);

    int n  = in_sizes[0];   // 24,084,480
    int n4 = n / 4;         // 6,021,120

    // 5880 ≡ 0 (mod 15): batch-invariant channel phase; 4 float4/thread exactly.
    int blocks = 5880;
    yolo_loss_kernel<<<blocks, 256, 0, stream>>>(pred, targ, out, n4);
}